// Round 10
// baseline (159.547 us; speedup 1.0000x reference)
//
#include <hip/hip_runtime.h>

#define D 64
#define EPS 2.0e-3f      // >= ~4x the merged-chain worst-case score-error bound

typedef __attribute__((ext_vector_type(8))) _Float16 f16x8;
typedef __attribute__((ext_vector_type(4))) float f32x4;
typedef __attribute__((ext_vector_type(16))) float f32x16;

// prep: pre-swizzled fp16 hi/lo centroid images + c2 + zero counter.
// hi = fp16(c); lo = fp16(c - hi) (unscaled; validated in r9).
// 32x32x16 B-fragment layout: col = lane&31, k_local = (lane>>5)*8 + j.
// Fragment (t, ks) covers centroids [t*32, t*32+32) x features [ks*16,+16).
// Image offset: ((t*4 + ks)*64 + lane)*8 f16 -> per step 4 KB contiguous,
// per-lane 16 B -> direct coalesced global_load_dwordx4.
__global__ void prep_kernel(const float* __restrict__ c, _Float16* __restrict__ chs,
                            _Float16* __restrict__ cls, float* __restrict__ c2,
                            int K, int* __restrict__ counter) {
    int t = blockIdx.x * blockDim.x + threadIdx.x;
    if (t == 0) *counter = 0;
    const int nfr = K * 8;
    if (t < nfr) {
        const int k = t >> 3, f = t & 7;          // f: feature octet [f*8, f*8+8)
        const int ks = f >> 1, half = f & 1;      // f*8 = ks*16 + half*8
        const int step = k >> 5, cb = k & 31;
        const int lane = half * 32 + cb;          // k_local = (lane>>5)*8 + j
        const size_t off = (size_t)((step * 4 + ks) * 64 + lane) * 8;
        const float* src = c + (size_t)k * D + f * 8;
        f16x8 h, l;
#pragma unroll
        for (int j = 0; j < 8; ++j) {
            float x = src[j];
            _Float16 hs = (_Float16)x;
            h[j] = hs;
            l[j] = (_Float16)(x - (float)hs);
        }
        *(f16x8*)(chs + off) = h;
        *(f16x8*)(cls + off) = l;
    }
    if (t < K) {
        const float4* cp = (const float4*)(c + (size_t)t * D);
        float s = 0.f;
#pragma unroll
        for (int i = 0; i < D / 4; ++i) {
            float4 v = cp[i];
            s += v.x * v.x; s += v.y * v.y; s += v.z * v.z; s += v.w * v.w;
        }
        c2[t] = s;
    }
}

// Pass 1: fp16-hi/lo MFMA scan + top-2 + bin write + near-tie flagging +
// exact fp32 residual.
// r9 diagnosis: across six structures the ONLY invariant work quantity is
// the 16x16x32 MFMA instruction stream (24 per 1024 scores); all land at
// 66-78 us with matrix-pipe time only ~25 us -> per-MFMA overhead is the
// wall. THIS REVISION: 32x32x16 shape -> 12 MFMAs per 1024 scores (half
// the instructions, 17% less pipe time). Wave = 32 rows x full K; block =
// 4 waves = 128 rows (no K-split / LDS merge needed). Direct global->reg
// B loads, depth-1 step pipeline (32 centroids/step), zero barriers.
// C/D: col=lane&31, row=(reg&3)+8*(reg>>2)+4*(lane>>5)  [HW-verified]
// A/B: row|col=lane&31, k=(lane>>5)*8+j per K=16 step    [doubled-K rule]
__global__ __launch_bounds__(256, 2) void pass1_kernel(
    const float* __restrict__ action, const _Float16* __restrict__ chs,
    const _Float16* __restrict__ cls, const float* __restrict__ c2,
    const float* __restrict__ centroids, float* __restrict__ out_bin,
    float* __restrict__ out_res, int* __restrict__ counter,
    int* __restrict__ flags, int N, int K) {
    __shared__ int sbk[128];

    const int tid  = threadIdx.x;
    const int wv   = tid >> 6;
    const int lane = tid & 63;
    const int colw = lane & 31;            // centroid col within step / A row
    const int khi  = lane >> 5;            // k-octet selector
    const int mb   = blockIdx.x * 128;
    const int m0   = mb + wv * 32;
    const int NT   = K / 32;               // 64 steps of 32 centroids

    const f16x8* gh = (const f16x8*)chs;
    const f16x8* gl = (const f16x8*)cls;

#define LOADP(H, L, CC, t_)                                                   \
    {                                                                         \
        const int cb = (t_) * 256 + lane;                                     \
        _Pragma("unroll") for (int ks = 0; ks < 4; ++ks) {                    \
            H[ks] = gh[cb + ks * 64];                                         \
            L[ks] = gl[cb + ks * 64];                                         \
        }                                                                     \
        CC = c2[(t_) * 32 + colw];                                            \
    }

    f16x8 Ph[4], Pl[4], Qh[4], Ql[4];
    float cc0, cc1;

    LOADP(Ph, Pl, cc0, 0)   // step 0 in flight under A-conversion

    // A fragments: a' = -2a -> fp16 hi + unscaled fp16 lo, registers once.
    // Row = m0 + colw; fragment ks covers features [ks*16,+16), this lane's
    // octet at ks*16 + khi*8.
    f16x8 ah[4], al[4];
    {
        const float* arow = action + (size_t)(m0 + colw) * D;
#pragma unroll
        for (int ks = 0; ks < 4; ++ks) {
            const float* src = arow + ks * 16 + khi * 8;
            f16x8 h, l;
#pragma unroll
            for (int j = 0; j < 8; ++j) {
                float x = -2.f * src[j];
                _Float16 hs = (_Float16)x;
                h[j] = hs;
                l[j] = (_Float16)(x - (float)hs);
            }
            ah[ks] = h;
            al[ks] = l;
        }
    }

    float b1[16], b2[16];
    int   bk[16];
#pragma unroll
    for (int e = 0; e < 16; ++e) {
        b1[e] = __builtin_inff(); b2[e] = __builtin_inff(); bk[e] = 0;
    }

#define COMPP(H, L, CC, t_)                                                   \
    {                                                                         \
        const int kk = (t_) * 32 + colw;                                      \
        f32x16 acc;                                                           \
        _Pragma("unroll") for (int e = 0; e < 16; ++e) acc[e] = CC;           \
        __builtin_amdgcn_s_setprio(1);                                        \
        _Pragma("unroll") for (int ks = 0; ks < 4; ++ks)                      \
            acc = __builtin_amdgcn_mfma_f32_32x32x16_f16(ah[ks], H[ks], acc, 0, 0, 0); \
        _Pragma("unroll") for (int ks = 0; ks < 4; ++ks)                      \
            acc = __builtin_amdgcn_mfma_f32_32x32x16_f16(ah[ks], L[ks], acc, 0, 0, 0); \
        _Pragma("unroll") for (int ks = 0; ks < 4; ++ks)                      \
            acc = __builtin_amdgcn_mfma_f32_32x32x16_f16(al[ks], H[ks], acc, 0, 0, 0); \
        __builtin_amdgcn_s_setprio(0);                                        \
        _Pragma("unroll") for (int e = 0; e < 16; ++e) {                      \
            const float s = acc[e];                                           \
            b2[e] = __builtin_amdgcn_fmed3f(s, b1[e], b2[e]);                 \
            const bool better = s < b1[e];                                    \
            b1[e] = fminf(b1[e], s);                                          \
            bk[e] = better ? kk : bk[e];                                      \
        }                                                                     \
    }

    for (int t = 0; t < NT; t += 2) {
        LOADP(Qh, Ql, cc1, t + 1)                      // prefetch t+1
        COMPP(Ph, Pl, cc0, t)
        {
            const int nt2 = (t + 2 < NT) ? (t + 2) : (NT - 1);  // tail: dead
            LOADP(Ph, Pl, cc0, nt2)                    // prefetch t+2
        }
        COMPP(Qh, Ql, cc1, t + 1)
    }
#undef COMPP
#undef LOADP

    // cross-lane top-2 merge over the 32 centroid columns.
    // offs 1..16 stay within each 32-lane half; lanes 0-31 and 32-63 hold
    // disjoint row sets, so the merge is per-row-set and complete.
#pragma unroll
    for (int off = 1; off < 32; off <<= 1) {
#pragma unroll
        for (int e = 0; e < 16; ++e) {
            float o1 = __shfl_xor(b1[e], off, 64);
            float o2 = __shfl_xor(b2[e], off, 64);
            int   ok = __shfl_xor(bk[e], off, 64);
            bool take = (o1 < b1[e]) || (o1 == b1[e] && ok < bk[e]);
            float nb2 = take ? fminf(b1[e], o2) : fminf(b2[e], o1);
            b1[e] = take ? o1 : b1[e];
            bk[e] = take ? ok : bk[e];
            b2[e] = nb2;
        }
    }

    if (colw == 0) {   // lanes 0 and 32: 16 rows each
#pragma unroll
        for (int e = 0; e < 16; ++e) {
            const int row = (e & 3) + 8 * (e >> 2) + 4 * khi;   // 0..31
            const int pl = wv * 32 + row;                        // 0..127
            sbk[pl] = bk[e];
            out_bin[mb + pl] = (float)bk[e];
            if (b2[e] - b1[e] < EPS) {
                int idx = atomicAdd(counter, 1);
                flags[idx] = mb + pl;
            }
        }
    }
    __syncthreads();

    // exact fp32 residuals for the block's 128 points (2048 float4s).
#pragma unroll
    for (int j = 0; j < 8; ++j) {
        const int idx = j * 256 + tid;
        const int row = idx >> 4, c4 = idx & 15;
        const int bki = sbk[row];
        float4 av = ((const float4*)(action + (size_t)(mb + row) * D))[c4];
        float4 cv = ((const float4*)centroids)[bki * 16 + c4];
        ((float4*)(out_res + (size_t)(mb + row) * D))[c4] =
            make_float4(av.x - cv.x, av.y - cv.y, av.z - cv.z, av.w - cv.w);
    }
}

// Exact fp32 rescan for flagged points. Block-per-point grid-stride.
// (round-0 known-good version; count ~60 at EPS 2e-3 -> a few us)
__global__ __launch_bounds__(256) void exact_kernel(
    const float* __restrict__ action, const float* __restrict__ centroids,
    const float* __restrict__ c2, const int* __restrict__ counter,
    const int* __restrict__ flags, float* __restrict__ out_bin,
    float* __restrict__ out_res, int K) {
    __shared__ float4 sa[D / 4];
    __shared__ float  swv[4];
    __shared__ int    swk[4];
    __shared__ int    s_bk;
    const int count = *counter;
    const int tid = threadIdx.x, lane = tid & 63, wid = tid >> 6;
    for (int i = blockIdx.x; i < count; i += gridDim.x) {
        const int n = flags[i];
        __syncthreads();
        if (tid < D / 4) sa[tid] = ((const float4*)(action + (size_t)n * D))[tid];
        __syncthreads();
        float best = __builtin_inff();
        int bbk = 0x7fffffff;
        for (int k = tid; k < K; k += 256) {
            const float4* cr = (const float4*)(centroids + (size_t)k * D);
            float d0 = 0.f, d1 = 0.f, d2 = 0.f, d3 = 0.f;
#pragma unroll
            for (int q = 0; q < 4; ++q) {
                float4 a0 = sa[q * 4 + 0], c0 = cr[q * 4 + 0];
                float4 a1 = sa[q * 4 + 1], c1 = cr[q * 4 + 1];
                float4 a2 = sa[q * 4 + 2], c2v = cr[q * 4 + 2];
                float4 a3 = sa[q * 4 + 3], c3 = cr[q * 4 + 3];
                d0 = fmaf(a0.x, c0.x, d0); d0 = fmaf(a0.y, c0.y, d0);
                d0 = fmaf(a0.z, c0.z, d0); d0 = fmaf(a0.w, c0.w, d0);
                d1 = fmaf(a1.x, c1.x, d1); d1 = fmaf(a1.y, c1.y, d1);
                d1 = fmaf(a1.z, c1.z, d1); d1 = fmaf(a1.w, c1.w, d1);
                d2 = fmaf(a2.x, c2v.x, d2); d2 = fmaf(a2.y, c2v.y, d2);
                d2 = fmaf(a2.z, c2v.z, d2); d2 = fmaf(a2.w, c2v.w, d2);
                d3 = fmaf(a3.x, c3.x, d3); d3 = fmaf(a3.y, c3.y, d3);
                d3 = fmaf(a3.z, c3.z, d3); d3 = fmaf(a3.w, c3.w, d3);
            }
            float dot = (d0 + d1) + (d2 + d3);
            float s = fmaf(-2.f, dot, c2[k]);
            if (s < best) { best = s; bbk = k; }  // ascending k: first-min
        }
#pragma unroll
        for (int off = 32; off > 0; off >>= 1) {
            float ov = __shfl_down(best, off, 64);
            int   ok = __shfl_down(bbk, off, 64);
            if (ov < best || (ov == best && ok < bbk)) { best = ov; bbk = ok; }
        }
        if (lane == 0) { swv[wid] = best; swk[wid] = bbk; }
        __syncthreads();
        if (tid == 0) {
            float bb = swv[0]; int bki = swk[0];
#pragma unroll
            for (int t = 1; t < 4; ++t)
                if (swv[t] < bb || (swv[t] == bb && swk[t] < bki)) {
                    bb = swv[t]; bki = swk[t];
                }
            out_bin[n] = (float)bki;
            s_bk = bki;
        }
        __syncthreads();
        if (tid < D / 4) {
            float4 a = sa[tid];
            float4 c = ((const float4*)(centroids + (size_t)s_bk * D))[tid];
            ((float4*)(out_res + (size_t)n * D))[tid] =
                make_float4(a.x - c.x, a.y - c.y, a.z - c.z, a.w - c.w);
        }
    }
}

extern "C" void kernel_launch(void* const* d_in, const int* in_sizes, int n_in,
                              void* d_out, int out_size, void* d_ws, size_t ws_size,
                              hipStream_t stream) {
    const float* action    = (const float*)d_in[0];  // [N, 64]
    const float* centroids = (const float*)d_in[1];  // [K, 64]
    const int N = in_sizes[0] / D;  // 65536
    const int K = in_sizes[1] / D;  // 2048

    float* out_bin = (float*)d_out;      // N floats: argmin index
    float* out_res = (float*)d_out + N;  // N*D residuals

    // ws layout (~0.8 MB)
    char* w = (char*)d_ws;
    float*     c2      = (float*)w;                       // 8 KB
    int*       counter = (int*)(w + 8192);                // 4 B (padded to 256)
    int*       flags   = (int*)(w + 8448);                // N*4 = 256 KB
    _Float16*  chs     = (_Float16*)(w + 8448 + 262144);  // K*D*2 = 256 KB (swizzled)
    _Float16*  cls     = chs + (size_t)K * D;             // 256 KB (swizzled)

    prep_kernel<<<(K * 8 + 255) / 256, 256, 0, stream>>>(centroids, chs, cls,
                                                         c2, K, counter);
    pass1_kernel<<<N / 128, 256, 0, stream>>>(action, chs, cls, c2, centroids,
                                              out_bin, out_res, counter, flags,
                                              N, K);
    exact_kernel<<<256, 256, 0, stream>>>(action, centroids, c2, counter, flags,
                                          out_bin, out_res, K);
}

// Round 11
// 151.820 us; speedup vs baseline: 1.0509x; 1.0509x over previous
//
#include <hip/hip_runtime.h>

#define D 64
#define EPS 2.0e-3f      // >= ~4x the merged-chain worst-case score-error bound

typedef __attribute__((ext_vector_type(8))) _Float16 f16x8;
typedef __attribute__((ext_vector_type(4))) float f32x4;

// prep: pre-swizzled fp16 hi/lo centroid images + c2 + zero counter.
// hi = fp16(c); lo = fp16(c - hi) (unscaled; validated in r9).
// Layout per (step,r): 64 lanes x 16 B contiguous -> direct coalesced
// global_load_dwordx4 per B-fragment. (identical to r9)
__global__ void prep_kernel(const float* __restrict__ c, _Float16* __restrict__ chs,
                            _Float16* __restrict__ cls, float* __restrict__ c2,
                            int K, int* __restrict__ counter) {
    int t = blockIdx.x * blockDim.x + threadIdx.x;
    if (t == 0) *counter = 0;
    const int nfr = K * 8;
    if (t < nfr) {
        const int k = t >> 3, f = t & 7;
        const int ks = f >> 2, quad = f & 3;
        const int chunk = k >> 6, kc = (k >> 4) & 3, col = k & 15;
        const size_t off = (size_t)chunk * 4096 +
                           (size_t)(((kc * 2 + ks) * 64 + quad * 16 + col) * 8);
        const float* src = c + (size_t)k * D + f * 8;
        f16x8 h, l;
#pragma unroll
        for (int j = 0; j < 8; ++j) {
            float x = src[j];
            _Float16 hs = (_Float16)x;
            h[j] = hs;
            l[j] = (_Float16)(x - (float)hs);    // unscaled lo
        }
        *(f16x8*)(chs + off) = h;
        *(f16x8*)(cls + off) = l;
    }
    if (t < K) {
        const float4* cp = (const float4*)(c + (size_t)t * D);
        float s = 0.f;
#pragma unroll
        for (int i = 0; i < D / 4; ++i) {
            float4 v = cp[i];
            s += v.x * v.x; s += v.y * v.y; s += v.z * v.z; s += v.w * v.w;
        }
        c2[t] = s;
    }
}

// Pass 1: fp16-hi/lo MFMA scan + top-2 + bin write + near-tie flagging +
// exact fp32 residual.
// r10 lesson: MFMA instruction count isn't the wall; dependency structure
// is. r9's program order (MFMA-chain(t) -> fold(t) -> chain(t+1)) makes
// each wave stall at every step boundary: in-order issue means the fold's
// RAW wait on acc(t) blocks the independent MFMAs of step t+1.
// THIS REVISION: r9's exact kernel with the fold SOFTWARE-PIPELINED one
// step: MFMA(t) -> MFMA(t+1) -> fold(t) -> MFMA(t+2) -> fold(t+1) ...
// using two named acc sets. Scores and fold ops are bit-identical to r9;
// only the instruction schedule changes.
__global__ __launch_bounds__(256, 2) void pass1_kernel(
    const float* __restrict__ action, const _Float16* __restrict__ chs,
    const _Float16* __restrict__ cls, const float* __restrict__ c2,
    const float* __restrict__ centroids, float* __restrict__ out_bin,
    float* __restrict__ out_res, int* __restrict__ counter,
    int* __restrict__ flags, int N, int K) {
    __shared__ float smb1[2][128], smb2[2][128];
    __shared__ int   smbk[2][128];
    __shared__ int   sbk[128];

    const int tid  = threadIdx.x;
    const int wv   = tid >> 6;
    const int kh   = wv >> 1;              // K-half this wave scans
    const int rg   = wv & 1;               // 64-row group this wave owns
    const int lane = tid & 63;
    const int col  = lane & 15;
    const int quad = lane >> 4;
    const int mb   = blockIdx.x * 128;
    const int m0   = mb + rg * 64;
    const int NTH  = K / 32;               // 64 steps per K-half
    const int t0   = kh * NTH;             // this wave's first step

    const f16x8* gh = (const f16x8*)chs;
    const f16x8* gl = (const f16x8*)cls;

#define LOADP(H0, H1, L0, L1, CC, t_)                                         \
    {                                                                         \
        const int cb = (t_) * 128 + lane;                                     \
        H0 = gh[cb];      H1 = gh[cb + 64];                                   \
        L0 = gl[cb];      L1 = gl[cb + 64];                                   \
        CC = c2[(t_) * 16 + col];                                             \
    }

    f16x8 p0h0, p0h1, p0l0, p0l1, p1h0, p1h1, p1l0, p1l1;
    float cc0, cc1;

    LOADP(p0h0, p0h1, p0l0, p0l1, cc0, t0)   // step t0 in flight under A-conv

    // A fragments: a' = -2a -> fp16 hi + unscaled fp16 lo, registers once.
    f16x8 ah[4][2], al[4][2];
#pragma unroll
    for (int mi = 0; mi < 4; ++mi) {
        const float* arow = action + (size_t)(m0 + mi * 16 + col) * D;
#pragma unroll
        for (int ks = 0; ks < 2; ++ks) {
            const float* src = arow + ks * 32 + quad * 8;
            f16x8 h, l;
#pragma unroll
            for (int j = 0; j < 8; ++j) {
                float x = -2.f * src[j];
                _Float16 hs = (_Float16)x;
                h[j] = hs;
                l[j] = (_Float16)(x - (float)hs);
            }
            ah[mi][ks] = h;
            al[mi][ks] = l;
        }
    }

    float b1[16], b2[16];
    int   bk[16];
#pragma unroll
    for (int e = 0; e < 16; ++e) {
        b1[e] = __builtin_inff(); b2[e] = __builtin_inff(); bk[e] = 0;
    }

    // MFMAS: produce ACC[4] (one f32x4 per mi tile) for a step.
    // Chain order identical to r9 -> bit-identical scores.
#define MFMAS(ACC, H0, H1, L0, L1, CC)                                        \
    {                                                                         \
        const f32x4 cc4 = {CC, CC, CC, CC};                                   \
        __builtin_amdgcn_s_setprio(1);                                        \
        _Pragma("unroll") for (int mi = 0; mi < 4; ++mi) {                    \
            f32x4 acc = __builtin_amdgcn_mfma_f32_16x16x32_f16(ah[mi][0], H0, cc4, 0, 0, 0); \
            acc = __builtin_amdgcn_mfma_f32_16x16x32_f16(ah[mi][0], L0, acc, 0, 0, 0);       \
            acc = __builtin_amdgcn_mfma_f32_16x16x32_f16(al[mi][0], H0, acc, 0, 0, 0);       \
            acc = __builtin_amdgcn_mfma_f32_16x16x32_f16(ah[mi][1], H1, acc, 0, 0, 0);       \
            acc = __builtin_amdgcn_mfma_f32_16x16x32_f16(ah[mi][1], L1, acc, 0, 0, 0);       \
            acc = __builtin_amdgcn_mfma_f32_16x16x32_f16(al[mi][1], H1, acc, 0, 0, 0);       \
            ACC[mi] = acc;                                                    \
        }                                                                     \
        __builtin_amdgcn_s_setprio(0);                                        \
    }

#define FOLD(ACC, t_)                                                         \
    {                                                                         \
        const int kk = (t_) * 16 + col;                                       \
        _Pragma("unroll") for (int mi = 0; mi < 4; ++mi) {                    \
            _Pragma("unroll") for (int r = 0; r < 4; ++r) {                   \
                const int e = mi * 4 + r;                                     \
                const float s = ACC[mi][r];                                   \
                b2[e] = __builtin_amdgcn_fmed3f(s, b1[e], b2[e]);             \
                const bool better = s < b1[e];                                \
                b1[e] = fminf(b1[e], s);                                      \
                bk[e] = better ? kk : bk[e];                                  \
            }                                                                 \
        }                                                                     \
    }

    f32x4 accA[4], accB[4];

    // prologue: load step t0+1, compute step t0 into accA.
    LOADP(p1h0, p1h1, p1l0, p1l1, cc1, t0 + 1)
    MFMAS(accA, p0h0, p0h1, p0l0, p0l1, cc0)

    for (int tl = 0; tl < NTH; tl += 2) {
        const int t = t0 + tl;
        const bool more = (tl + 2 < NTH);
        if (more) LOADP(p0h0, p0h1, p0l0, p0l1, cc0, t + 2)   // prefetch t+2
        MFMAS(accB, p1h0, p1h1, p1l0, p1l1, cc1)              // step t+1
        FOLD(accA, t)                                          // fold t (covered)
        if (more) {
            LOADP(p1h0, p1h1, p1l0, p1l1, cc1, t + 3)         // prefetch t+3
            MFMAS(accA, p0h0, p0h1, p0l0, p0l1, cc0)          // step t+2
        }
        FOLD(accB, t + 1)                                      // fold t+1
    }
#undef MFMAS
#undef FOLD
#undef LOADP

    // cross-lane top-2 merge over the 16 centroid columns (within K-half)
#pragma unroll
    for (int off = 1; off < 16; off <<= 1) {
#pragma unroll
        for (int e = 0; e < 16; ++e) {
            float o1 = __shfl_xor(b1[e], off, 64);
            float o2 = __shfl_xor(b2[e], off, 64);
            int   ok = __shfl_xor(bk[e], off, 64);
            bool take = (o1 < b1[e]) || (o1 == b1[e] && ok < bk[e]);
            float nb2 = take ? fminf(b1[e], o2) : fminf(b2[e], o1);
            b1[e] = take ? o1 : b1[e];
            bk[e] = take ? ok : bk[e];
            b2[e] = nb2;
        }
    }

    // per-half results -> LDS
    if (col == 0) {
#pragma unroll
        for (int e = 0; e < 16; ++e) {
            const int mi = e >> 2, r = e & 3;
            const int p = rg * 64 + mi * 16 + quad * 4 + r;   // 0..127
            smb1[kh][p] = b1[e];
            smb2[kh][p] = b2[e];
            smbk[kh][p] = bk[e];
        }
    }
    __syncthreads();

    // merge the two K-halves per point (lexicographic (s,k); half 0 holds
    // the lower k-range, so ties resolve to it naturally).
    if (tid < 128) {
        const int p = tid;
        float b1a = smb1[0][p], b2a = smb2[0][p];
        int   bka = smbk[0][p];
        float b1b = smb1[1][p], b2b = smb2[1][p];
        int   bkb = smbk[1][p];
        bool take = (b1b < b1a) || (b1b == b1a && bkb < bka);
        float m1 = take ? b1b : b1a;
        int   mk = take ? bkb : bka;
        float m2 = take ? fminf(b1a, b2b) : fminf(b2a, b1b);
        sbk[p] = mk;
        out_bin[mb + p] = (float)mk;
        if (m2 - m1 < EPS) {
            int idx = atomicAdd(counter, 1);
            flags[idx] = mb + p;
        }
    }
    __syncthreads();

    // exact fp32 residuals for the block's 128 points (2048 float4s).
#pragma unroll
    for (int j = 0; j < 8; ++j) {
        const int idx = j * 256 + tid;
        const int row = idx >> 4, c4 = idx & 15;
        const int bki = sbk[row];
        float4 av = ((const float4*)(action + (size_t)(mb + row) * D))[c4];
        float4 cv = ((const float4*)centroids)[bki * 16 + c4];
        ((float4*)(out_res + (size_t)(mb + row) * D))[c4] =
            make_float4(av.x - cv.x, av.y - cv.y, av.z - cv.z, av.w - cv.w);
    }
}

// Exact fp32 rescan for flagged points. Block-per-point grid-stride.
// (round-0 known-good version; count ~60 at EPS 2e-3 -> a few us)
__global__ __launch_bounds__(256) void exact_kernel(
    const float* __restrict__ action, const float* __restrict__ centroids,
    const float* __restrict__ c2, const int* __restrict__ counter,
    const int* __restrict__ flags, float* __restrict__ out_bin,
    float* __restrict__ out_res, int K) {
    __shared__ float4 sa[D / 4];
    __shared__ float  swv[4];
    __shared__ int    swk[4];
    __shared__ int    s_bk;
    const int count = *counter;
    const int tid = threadIdx.x, lane = tid & 63, wid = tid >> 6;
    for (int i = blockIdx.x; i < count; i += gridDim.x) {
        const int n = flags[i];
        __syncthreads();
        if (tid < D / 4) sa[tid] = ((const float4*)(action + (size_t)n * D))[tid];
        __syncthreads();
        float best = __builtin_inff();
        int bbk = 0x7fffffff;
        for (int k = tid; k < K; k += 256) {
            const float4* cr = (const float4*)(centroids + (size_t)k * D);
            float d0 = 0.f, d1 = 0.f, d2 = 0.f, d3 = 0.f;
#pragma unroll
            for (int q = 0; q < 4; ++q) {
                float4 a0 = sa[q * 4 + 0], c0 = cr[q * 4 + 0];
                float4 a1 = sa[q * 4 + 1], c1 = cr[q * 4 + 1];
                float4 a2 = sa[q * 4 + 2], c2v = cr[q * 4 + 2];
                float4 a3 = sa[q * 4 + 3], c3 = cr[q * 4 + 3];
                d0 = fmaf(a0.x, c0.x, d0); d0 = fmaf(a0.y, c0.y, d0);
                d0 = fmaf(a0.z, c0.z, d0); d0 = fmaf(a0.w, c0.w, d0);
                d1 = fmaf(a1.x, c1.x, d1); d1 = fmaf(a1.y, c1.y, d1);
                d1 = fmaf(a1.z, c1.z, d1); d1 = fmaf(a1.w, c1.w, d1);
                d2 = fmaf(a2.x, c2v.x, d2); d2 = fmaf(a2.y, c2v.y, d2);
                d2 = fmaf(a2.z, c2v.z, d2); d2 = fmaf(a2.w, c2v.w, d2);
                d3 = fmaf(a3.x, c3.x, d3); d3 = fmaf(a3.y, c3.y, d3);
                d3 = fmaf(a3.z, c3.z, d3); d3 = fmaf(a3.w, c3.w, d3);
            }
            float dot = (d0 + d1) + (d2 + d3);
            float s = fmaf(-2.f, dot, c2[k]);
            if (s < best) { best = s; bbk = k; }  // ascending k: first-min
        }
#pragma unroll
        for (int off = 32; off > 0; off >>= 1) {
            float ov = __shfl_down(best, off, 64);
            int   ok = __shfl_down(bbk, off, 64);
            if (ov < best || (ov == best && ok < bbk)) { best = ov; bbk = ok; }
        }
        if (lane == 0) { swv[wid] = best; swk[wid] = bbk; }
        __syncthreads();
        if (tid == 0) {
            float bb = swv[0]; int bki = swk[0];
#pragma unroll
            for (int t = 1; t < 4; ++t)
                if (swv[t] < bb || (swv[t] == bb && swk[t] < bki)) {
                    bb = swv[t]; bki = swk[t];
                }
            out_bin[n] = (float)bki;
            s_bk = bki;
        }
        __syncthreads();
        if (tid < D / 4) {
            float4 a = sa[tid];
            float4 c = ((const float4*)(centroids + (size_t)s_bk * D))[tid];
            ((float4*)(out_res + (size_t)n * D))[tid] =
                make_float4(a.x - c.x, a.y - c.y, a.z - c.z, a.w - c.w);
        }
    }
}

extern "C" void kernel_launch(void* const* d_in, const int* in_sizes, int n_in,
                              void* d_out, int out_size, void* d_ws, size_t ws_size,
                              hipStream_t stream) {
    const float* action    = (const float*)d_in[0];  // [N, 64]
    const float* centroids = (const float*)d_in[1];  // [K, 64]
    const int N = in_sizes[0] / D;  // 65536
    const int K = in_sizes[1] / D;  // 2048

    float* out_bin = (float*)d_out;      // N floats: argmin index
    float* out_res = (float*)d_out + N;  // N*D residuals

    // ws layout (~0.8 MB)
    char* w = (char*)d_ws;
    float*     c2      = (float*)w;                       // 8 KB
    int*       counter = (int*)(w + 8192);                // 4 B (padded to 256)
    int*       flags   = (int*)(w + 8448);                // N*4 = 256 KB
    _Float16*  chs     = (_Float16*)(w + 8448 + 262144);  // K*D*2 = 256 KB (swizzled)
    _Float16*  cls     = chs + (size_t)K * D;             // 256 KB (swizzled)

    prep_kernel<<<(K * 8 + 255) / 256, 256, 0, stream>>>(centroids, chs, cls,
                                                         c2, K, counter);
    pass1_kernel<<<N / 128, 256, 0, stream>>>(action, chs, cls, c2, centroids,
                                              out_bin, out_res, counter, flags,
                                              N, K);
    exact_kernel<<<256, 256, 0, stream>>>(action, centroids, c2, counter, flags,
                                          out_bin, out_res, K);
}

// Round 12
// 146.055 us; speedup vs baseline: 1.0924x; 1.0395x over previous
//
#include <hip/hip_runtime.h>

#define D 64
#define EPS 2.0e-3f      // >= ~4x the merged-chain worst-case score-error bound

typedef __attribute__((ext_vector_type(8))) _Float16 f16x8;
typedef __attribute__((ext_vector_type(4))) float f32x4;

// prep: pre-swizzled fp16 hi/lo centroid images + c2 + zero counter.
// hi = fp16(c); lo = fp16(c - hi) (unscaled; validated in r9).
// Layout per (step,r): 64 lanes x 16 B contiguous -> direct coalesced
// global_load_dwordx4 per B-fragment. (identical to r9)
__global__ void prep_kernel(const float* __restrict__ c, _Float16* __restrict__ chs,
                            _Float16* __restrict__ cls, float* __restrict__ c2,
                            int K, int* __restrict__ counter) {
    int t = blockIdx.x * blockDim.x + threadIdx.x;
    if (t == 0) *counter = 0;
    const int nfr = K * 8;
    if (t < nfr) {
        const int k = t >> 3, f = t & 7;
        const int ks = f >> 2, quad = f & 3;
        const int chunk = k >> 6, kc = (k >> 4) & 3, col = k & 15;
        const size_t off = (size_t)chunk * 4096 +
                           (size_t)(((kc * 2 + ks) * 64 + quad * 16 + col) * 8);
        const float* src = c + (size_t)k * D + f * 8;
        f16x8 h, l;
#pragma unroll
        for (int j = 0; j < 8; ++j) {
            float x = src[j];
            _Float16 hs = (_Float16)x;
            h[j] = hs;
            l[j] = (_Float16)(x - (float)hs);    // unscaled lo
        }
        *(f16x8*)(chs + off) = h;
        *(f16x8*)(cls + off) = l;
    }
    if (t < K) {
        const float4* cp = (const float4*)(c + (size_t)t * D);
        float s = 0.f;
#pragma unroll
        for (int i = 0; i < D / 4; ++i) {
            float4 v = cp[i];
            s += v.x * v.x; s += v.y * v.y; s += v.z * v.z; s += v.w * v.w;
        }
        c2[t] = s;
    }
}

// Pass 1: fp16-hi/lo MFMA scan + top-2 + bin write + near-tie flagging +
// exact fp32 residual.
// Base = r9 (best, 66 us). Counter re-read: VALUBusy includes MFMA on
// gfx950, so true VALU is only ~12-15% and ~50% of SIMD cycles are stalls
// in EVERY structure tried. Surviving theory: B-load latency at effective
// depth-1 prefetch with phase-locked waves (the 512 KB table gets evicted
// from L2 by the ~33 MB/iter action/out streams -> L3-latency loads).
// THIS REVISION: depth-3 register prefetch. Four named B-sets, 4-step
// body; each COMPP waits only on loads issued 3 COMPPs earlier. COMPP is
// byte-identical to r9 (same chain order, fold, scan order).
__global__ __launch_bounds__(256, 2) void pass1_kernel(
    const float* __restrict__ action, const _Float16* __restrict__ chs,
    const _Float16* __restrict__ cls, const float* __restrict__ c2,
    const float* __restrict__ centroids, float* __restrict__ out_bin,
    float* __restrict__ out_res, int* __restrict__ counter,
    int* __restrict__ flags, int N, int K) {
    __shared__ float smb1[2][128], smb2[2][128];
    __shared__ int   smbk[2][128];
    __shared__ int   sbk[128];

    const int tid  = threadIdx.x;
    const int wv   = tid >> 6;
    const int kh   = wv >> 1;              // K-half this wave scans
    const int rg   = wv & 1;               // 64-row group this wave owns
    const int lane = tid & 63;
    const int col  = lane & 15;
    const int quad = lane >> 4;
    const int mb   = blockIdx.x * 128;
    const int m0   = mb + rg * 64;
    const int NTH  = K / 32;               // 64 steps per K-half
    const int t0   = kh * NTH;             // this wave's first step
    const int tmax = t0 + NTH - 1;

    const f16x8* gh = (const f16x8*)chs;
    const f16x8* gl = (const f16x8*)cls;

#define LOADP(H0, H1, L0, L1, CC, t_)                                         \
    {                                                                         \
        const int tc = ((t_) < tmax) ? (t_) : tmax;    /* tail: clamp dead */ \
        const int cb = tc * 128 + lane;                                       \
        H0 = gh[cb];      H1 = gh[cb + 64];                                   \
        L0 = gl[cb];      L1 = gl[cb + 64];                                   \
        CC = c2[tc * 16 + col];                                               \
    }

    f16x8 s0h0, s0h1, s0l0, s0l1, s1h0, s1h1, s1l0, s1l1;
    f16x8 s2h0, s2h1, s2l0, s2l1, s3h0, s3h1, s3l0, s3l1;
    float cc0, cc1, cc2, cc3;

    // prologue: steps t0..t0+2 in flight under A-conversion.
    LOADP(s0h0, s0h1, s0l0, s0l1, cc0, t0)
    LOADP(s1h0, s1h1, s1l0, s1l1, cc1, t0 + 1)
    LOADP(s2h0, s2h1, s2l0, s2l1, cc2, t0 + 2)

    // A fragments: a' = -2a -> fp16 hi + unscaled fp16 lo, registers once.
    f16x8 ah[4][2], al[4][2];
#pragma unroll
    for (int mi = 0; mi < 4; ++mi) {
        const float* arow = action + (size_t)(m0 + mi * 16 + col) * D;
#pragma unroll
        for (int ks = 0; ks < 2; ++ks) {
            const float* src = arow + ks * 32 + quad * 8;
            f16x8 h, l;
#pragma unroll
            for (int j = 0; j < 8; ++j) {
                float x = -2.f * src[j];
                _Float16 hs = (_Float16)x;
                h[j] = hs;
                l[j] = (_Float16)(x - (float)hs);
            }
            ah[mi][ks] = h;
            al[mi][ks] = l;
        }
    }

    float b1[16], b2[16];
    int   bk[16];
#pragma unroll
    for (int e = 0; e < 16; ++e) {
        b1[e] = __builtin_inff(); b2[e] = __builtin_inff(); bk[e] = 0;
    }

    // COMPP: byte-identical to r9 -> bit-identical scores & fold.
#define COMPP(H0, H1, L0, L1, CC, t_)                                         \
    {                                                                         \
        const int kk = (t_) * 16 + col;                                       \
        const f32x4 cc4 = {CC, CC, CC, CC};                                   \
        _Pragma("unroll") for (int mi = 0; mi < 4; ++mi) {                    \
            __builtin_amdgcn_s_setprio(1);                                    \
            f32x4 acc = __builtin_amdgcn_mfma_f32_16x16x32_f16(ah[mi][0], H0, cc4, 0, 0, 0); \
            acc = __builtin_amdgcn_mfma_f32_16x16x32_f16(ah[mi][0], L0, acc, 0, 0, 0);       \
            acc = __builtin_amdgcn_mfma_f32_16x16x32_f16(al[mi][0], H0, acc, 0, 0, 0);       \
            acc = __builtin_amdgcn_mfma_f32_16x16x32_f16(ah[mi][1], H1, acc, 0, 0, 0);       \
            acc = __builtin_amdgcn_mfma_f32_16x16x32_f16(ah[mi][1], L1, acc, 0, 0, 0);       \
            acc = __builtin_amdgcn_mfma_f32_16x16x32_f16(al[mi][1], H1, acc, 0, 0, 0);       \
            __builtin_amdgcn_s_setprio(0);                                    \
            _Pragma("unroll") for (int r = 0; r < 4; ++r) {                   \
                const int e = mi * 4 + r;                                     \
                const float s = acc[r];                                       \
                b2[e] = __builtin_amdgcn_fmed3f(s, b1[e], b2[e]);             \
                const bool better = s < b1[e];                                \
                b1[e] = fminf(b1[e], s);                                      \
                bk[e] = better ? kk : bk[e];                                  \
            }                                                                 \
        }                                                                     \
    }

    // 4-step body, depth-3 prefetch: COMPP(S, t) waits only on loads
    // issued 3 COMPPs ago (>= ~1500 cyc of cover). NTH % 4 == 0.
    for (int tl = 0; tl < NTH; tl += 4) {
        const int t = t0 + tl;
        LOADP(s3h0, s3h1, s3l0, s3l1, cc3, t + 3)
        COMPP(s0h0, s0h1, s0l0, s0l1, cc0, t)
        LOADP(s0h0, s0h1, s0l0, s0l1, cc0, t + 4)
        COMPP(s1h0, s1h1, s1l0, s1l1, cc1, t + 1)
        LOADP(s1h0, s1h1, s1l0, s1l1, cc1, t + 5)
        COMPP(s2h0, s2h1, s2l0, s2l1, cc2, t + 2)
        LOADP(s2h0, s2h1, s2l0, s2l1, cc2, t + 6)
        COMPP(s3h0, s3h1, s3l0, s3l1, cc3, t + 3)
    }
#undef COMPP
#undef LOADP

    // cross-lane top-2 merge over the 16 centroid columns (within K-half)
#pragma unroll
    for (int off = 1; off < 16; off <<= 1) {
#pragma unroll
        for (int e = 0; e < 16; ++e) {
            float o1 = __shfl_xor(b1[e], off, 64);
            float o2 = __shfl_xor(b2[e], off, 64);
            int   ok = __shfl_xor(bk[e], off, 64);
            bool take = (o1 < b1[e]) || (o1 == b1[e] && ok < bk[e]);
            float nb2 = take ? fminf(b1[e], o2) : fminf(b2[e], o1);
            b1[e] = take ? o1 : b1[e];
            bk[e] = take ? ok : bk[e];
            b2[e] = nb2;
        }
    }

    // per-half results -> LDS
    if (col == 0) {
#pragma unroll
        for (int e = 0; e < 16; ++e) {
            const int mi = e >> 2, r = e & 3;
            const int p = rg * 64 + mi * 16 + quad * 4 + r;   // 0..127
            smb1[kh][p] = b1[e];
            smb2[kh][p] = b2[e];
            smbk[kh][p] = bk[e];
        }
    }
    __syncthreads();

    // merge the two K-halves per point (lexicographic (s,k); half 0 holds
    // the lower k-range, so ties resolve to it naturally).
    if (tid < 128) {
        const int p = tid;
        float b1a = smb1[0][p], b2a = smb2[0][p];
        int   bka = smbk[0][p];
        float b1b = smb1[1][p], b2b = smb2[1][p];
        int   bkb = smbk[1][p];
        bool take = (b1b < b1a) || (b1b == b1a && bkb < bka);
        float m1 = take ? b1b : b1a;
        int   mk = take ? bkb : bka;
        float m2 = take ? fminf(b1a, b2b) : fminf(b2a, b1b);
        sbk[p] = mk;
        out_bin[mb + p] = (float)mk;
        if (m2 - m1 < EPS) {
            int idx = atomicAdd(counter, 1);
            flags[idx] = mb + p;
        }
    }
    __syncthreads();

    // exact fp32 residuals for the block's 128 points (2048 float4s).
#pragma unroll
    for (int j = 0; j < 8; ++j) {
        const int idx = j * 256 + tid;
        const int row = idx >> 4, c4 = idx & 15;
        const int bki = sbk[row];
        float4 av = ((const float4*)(action + (size_t)(mb + row) * D))[c4];
        float4 cv = ((const float4*)centroids)[bki * 16 + c4];
        ((float4*)(out_res + (size_t)(mb + row) * D))[c4] =
            make_float4(av.x - cv.x, av.y - cv.y, av.z - cv.z, av.w - cv.w);
    }
}

// Exact fp32 rescan for flagged points. Block-per-point grid-stride.
// (round-0 known-good version; count ~60 at EPS 2e-3 -> a few us)
__global__ __launch_bounds__(256) void exact_kernel(
    const float* __restrict__ action, const float* __restrict__ centroids,
    const float* __restrict__ c2, const int* __restrict__ counter,
    const int* __restrict__ flags, float* __restrict__ out_bin,
    float* __restrict__ out_res, int K) {
    __shared__ float4 sa[D / 4];
    __shared__ float  swv[4];
    __shared__ int    swk[4];
    __shared__ int    s_bk;
    const int count = *counter;
    const int tid = threadIdx.x, lane = tid & 63, wid = tid >> 6;
    for (int i = blockIdx.x; i < count; i += gridDim.x) {
        const int n = flags[i];
        __syncthreads();
        if (tid < D / 4) sa[tid] = ((const float4*)(action + (size_t)n * D))[tid];
        __syncthreads();
        float best = __builtin_inff();
        int bbk = 0x7fffffff;
        for (int k = tid; k < K; k += 256) {
            const float4* cr = (const float4*)(centroids + (size_t)k * D);
            float d0 = 0.f, d1 = 0.f, d2 = 0.f, d3 = 0.f;
#pragma unroll
            for (int q = 0; q < 4; ++q) {
                float4 a0 = sa[q * 4 + 0], c0 = cr[q * 4 + 0];
                float4 a1 = sa[q * 4 + 1], c1 = cr[q * 4 + 1];
                float4 a2 = sa[q * 4 + 2], c2v = cr[q * 4 + 2];
                float4 a3 = sa[q * 4 + 3], c3 = cr[q * 4 + 3];
                d0 = fmaf(a0.x, c0.x, d0); d0 = fmaf(a0.y, c0.y, d0);
                d0 = fmaf(a0.z, c0.z, d0); d0 = fmaf(a0.w, c0.w, d0);
                d1 = fmaf(a1.x, c1.x, d1); d1 = fmaf(a1.y, c1.y, d1);
                d1 = fmaf(a1.z, c1.z, d1); d1 = fmaf(a1.w, c1.w, d1);
                d2 = fmaf(a2.x, c2v.x, d2); d2 = fmaf(a2.y, c2v.y, d2);
                d2 = fmaf(a2.z, c2v.z, d2); d2 = fmaf(a2.w, c2v.w, d2);
                d3 = fmaf(a3.x, c3.x, d3); d3 = fmaf(a3.y, c3.y, d3);
                d3 = fmaf(a3.z, c3.z, d3); d3 = fmaf(a3.w, c3.w, d3);
            }
            float dot = (d0 + d1) + (d2 + d3);
            float s = fmaf(-2.f, dot, c2[k]);
            if (s < best) { best = s; bbk = k; }  // ascending k: first-min
        }
#pragma unroll
        for (int off = 32; off > 0; off >>= 1) {
            float ov = __shfl_down(best, off, 64);
            int   ok = __shfl_down(bbk, off, 64);
            if (ov < best || (ov == best && ok < bbk)) { best = ov; bbk = ok; }
        }
        if (lane == 0) { swv[wid] = best; swk[wid] = bbk; }
        __syncthreads();
        if (tid == 0) {
            float bb = swv[0]; int bki = swk[0];
#pragma unroll
            for (int t = 1; t < 4; ++t)
                if (swv[t] < bb || (swv[t] == bb && swk[t] < bki)) {
                    bb = swv[t]; bki = swk[t];
                }
            out_bin[n] = (float)bki;
            s_bk = bki;
        }
        __syncthreads();
        if (tid < D / 4) {
            float4 a = sa[tid];
            float4 c = ((const float4*)(centroids + (size_t)s_bk * D))[tid];
            ((float4*)(out_res + (size_t)n * D))[tid] =
                make_float4(a.x - c.x, a.y - c.y, a.z - c.z, a.w - c.w);
        }
    }
}

extern "C" void kernel_launch(void* const* d_in, const int* in_sizes, int n_in,
                              void* d_out, int out_size, void* d_ws, size_t ws_size,
                              hipStream_t stream) {
    const float* action    = (const float*)d_in[0];  // [N, 64]
    const float* centroids = (const float*)d_in[1];  // [K, 64]
    const int N = in_sizes[0] / D;  // 65536
    const int K = in_sizes[1] / D;  // 2048

    float* out_bin = (float*)d_out;      // N floats: argmin index
    float* out_res = (float*)d_out + N;  // N*D residuals

    // ws layout (~0.8 MB)
    char* w = (char*)d_ws;
    float*     c2      = (float*)w;                       // 8 KB
    int*       counter = (int*)(w + 8192);                // 4 B (padded to 256)
    int*       flags   = (int*)(w + 8448);                // N*4 = 256 KB
    _Float16*  chs     = (_Float16*)(w + 8448 + 262144);  // K*D*2 = 256 KB (swizzled)
    _Float16*  cls     = chs + (size_t)K * D;             // 256 KB (swizzled)

    prep_kernel<<<(K * 8 + 255) / 256, 256, 0, stream>>>(centroids, chs, cls,
                                                         c2, K, counter);
    pass1_kernel<<<N / 128, 256, 0, stream>>>(action, chs, cls, c2, centroids,
                                              out_bin, out_res, counter, flags,
                                              N, K);
    exact_kernel<<<256, 256, 0, stream>>>(action, centroids, c2, counter, flags,
                                          out_bin, out_res, K);
}

// Round 13
// 145.075 us; speedup vs baseline: 1.0998x; 1.0068x over previous
//
#include <hip/hip_runtime.h>

#define D 64
#define EPS 2.0e-3f      // >= ~4x the merged-chain worst-case score-error bound

typedef __attribute__((ext_vector_type(8))) _Float16 f16x8;
typedef __attribute__((ext_vector_type(4))) float f32x4;

// prep: pre-swizzled fp16 hi/lo centroid images + c2 + zero counter.
// hi = fp16(c); lo = fp16(c - hi) (unscaled; validated in r9).
// Layout per (step,r): 64 lanes x 16 B contiguous -> direct coalesced
// global_load_dwordx4 per B-fragment. (identical to r9)
__global__ void prep_kernel(const float* __restrict__ c, _Float16* __restrict__ chs,
                            _Float16* __restrict__ cls, float* __restrict__ c2,
                            int K, int* __restrict__ counter) {
    int t = blockIdx.x * blockDim.x + threadIdx.x;
    if (t == 0) *counter = 0;
    const int nfr = K * 8;
    if (t < nfr) {
        const int k = t >> 3, f = t & 7;
        const int ks = f >> 2, quad = f & 3;
        const int chunk = k >> 6, kc = (k >> 4) & 3, col = k & 15;
        const size_t off = (size_t)chunk * 4096 +
                           (size_t)(((kc * 2 + ks) * 64 + quad * 16 + col) * 8);
        const float* src = c + (size_t)k * D + f * 8;
        f16x8 h, l;
#pragma unroll
        for (int j = 0; j < 8; ++j) {
            float x = src[j];
            _Float16 hs = (_Float16)x;
            h[j] = hs;
            l[j] = (_Float16)(x - (float)hs);    // unscaled lo
        }
        *(f16x8*)(chs + off) = h;
        *(f16x8*)(cls + off) = l;
    }
    if (t < K) {
        const float4* cp = (const float4*)(c + (size_t)t * D);
        float s = 0.f;
#pragma unroll
        for (int i = 0; i < D / 4; ++i) {
            float4 v = cp[i];
            s += v.x * v.x; s += v.y * v.y; s += v.z * v.z; s += v.w * v.w;
        }
        c2[t] = s;
    }
}

// Pass 1: fp16-hi/lo MFMA scan + top-2 + bin write + near-tie flagging +
// exact fp32 residual.
// = r12 (best, 65.8 us) with s_setprio REMOVED — the one never-ablated
// variable. Mechanism under test: with 2 same-stream waves/SIMD, wave A's
// setprio(1) during MFMA deprioritizes wave B's fold phase and vice versa,
// enforcing mutual exclusion of the MFMA and VALU phases (the measured
// "MFMA-time + VALU-time add" signature). m190 measured setprio negative
// on lockstep GEMM; it only pays on phase-split schedules (m218b).
__global__ __launch_bounds__(256, 2) void pass1_kernel(
    const float* __restrict__ action, const _Float16* __restrict__ chs,
    const _Float16* __restrict__ cls, const float* __restrict__ c2,
    const float* __restrict__ centroids, float* __restrict__ out_bin,
    float* __restrict__ out_res, int* __restrict__ counter,
    int* __restrict__ flags, int N, int K) {
    __shared__ float smb1[2][128], smb2[2][128];
    __shared__ int   smbk[2][128];
    __shared__ int   sbk[128];

    const int tid  = threadIdx.x;
    const int wv   = tid >> 6;
    const int kh   = wv >> 1;              // K-half this wave scans
    const int rg   = wv & 1;               // 64-row group this wave owns
    const int lane = tid & 63;
    const int col  = lane & 15;
    const int quad = lane >> 4;
    const int mb   = blockIdx.x * 128;
    const int m0   = mb + rg * 64;
    const int NTH  = K / 32;               // 64 steps per K-half
    const int t0   = kh * NTH;             // this wave's first step
    const int tmax = t0 + NTH - 1;

    const f16x8* gh = (const f16x8*)chs;
    const f16x8* gl = (const f16x8*)cls;

#define LOADP(H0, H1, L0, L1, CC, t_)                                         \
    {                                                                         \
        const int tc = ((t_) < tmax) ? (t_) : tmax;    /* tail: clamp dead */ \
        const int cb = tc * 128 + lane;                                       \
        H0 = gh[cb];      H1 = gh[cb + 64];                                   \
        L0 = gl[cb];      L1 = gl[cb + 64];                                   \
        CC = c2[tc * 16 + col];                                               \
    }

    f16x8 s0h0, s0h1, s0l0, s0l1, s1h0, s1h1, s1l0, s1l1;
    f16x8 s2h0, s2h1, s2l0, s2l1, s3h0, s3h1, s3l0, s3l1;
    float cc0, cc1, cc2, cc3;

    // prologue: steps t0..t0+2 in flight under A-conversion.
    LOADP(s0h0, s0h1, s0l0, s0l1, cc0, t0)
    LOADP(s1h0, s1h1, s1l0, s1l1, cc1, t0 + 1)
    LOADP(s2h0, s2h1, s2l0, s2l1, cc2, t0 + 2)

    // A fragments: a' = -2a -> fp16 hi + unscaled fp16 lo, registers once.
    f16x8 ah[4][2], al[4][2];
#pragma unroll
    for (int mi = 0; mi < 4; ++mi) {
        const float* arow = action + (size_t)(m0 + mi * 16 + col) * D;
#pragma unroll
        for (int ks = 0; ks < 2; ++ks) {
            const float* src = arow + ks * 32 + quad * 8;
            f16x8 h, l;
#pragma unroll
            for (int j = 0; j < 8; ++j) {
                float x = -2.f * src[j];
                _Float16 hs = (_Float16)x;
                h[j] = hs;
                l[j] = (_Float16)(x - (float)hs);
            }
            ah[mi][ks] = h;
            al[mi][ks] = l;
        }
    }

    float b1[16], b2[16];
    int   bk[16];
#pragma unroll
    for (int e = 0; e < 16; ++e) {
        b1[e] = __builtin_inff(); b2[e] = __builtin_inff(); bk[e] = 0;
    }

    // COMPP: identical chain order / fold to r9+r12 -> bit-identical output.
    // (setprio removed — the only change this round.)
#define COMPP(H0, H1, L0, L1, CC, t_)                                         \
    {                                                                         \
        const int kk = (t_) * 16 + col;                                       \
        const f32x4 cc4 = {CC, CC, CC, CC};                                   \
        _Pragma("unroll") for (int mi = 0; mi < 4; ++mi) {                    \
            f32x4 acc = __builtin_amdgcn_mfma_f32_16x16x32_f16(ah[mi][0], H0, cc4, 0, 0, 0); \
            acc = __builtin_amdgcn_mfma_f32_16x16x32_f16(ah[mi][0], L0, acc, 0, 0, 0);       \
            acc = __builtin_amdgcn_mfma_f32_16x16x32_f16(al[mi][0], H0, acc, 0, 0, 0);       \
            acc = __builtin_amdgcn_mfma_f32_16x16x32_f16(ah[mi][1], H1, acc, 0, 0, 0);       \
            acc = __builtin_amdgcn_mfma_f32_16x16x32_f16(ah[mi][1], L1, acc, 0, 0, 0);       \
            acc = __builtin_amdgcn_mfma_f32_16x16x32_f16(al[mi][1], H1, acc, 0, 0, 0);       \
            _Pragma("unroll") for (int r = 0; r < 4; ++r) {                   \
                const int e = mi * 4 + r;                                     \
                const float s = acc[r];                                       \
                b2[e] = __builtin_amdgcn_fmed3f(s, b1[e], b2[e]);             \
                const bool better = s < b1[e];                                \
                b1[e] = fminf(b1[e], s);                                      \
                bk[e] = better ? kk : bk[e];                                  \
            }                                                                 \
        }                                                                     \
    }

    // 4-step body, depth-3 prefetch (r12 structure). NTH % 4 == 0.
    for (int tl = 0; tl < NTH; tl += 4) {
        const int t = t0 + tl;
        LOADP(s3h0, s3h1, s3l0, s3l1, cc3, t + 3)
        COMPP(s0h0, s0h1, s0l0, s0l1, cc0, t)
        LOADP(s0h0, s0h1, s0l0, s0l1, cc0, t + 4)
        COMPP(s1h0, s1h1, s1l0, s1l1, cc1, t + 1)
        LOADP(s1h0, s1h1, s1l0, s1l1, cc1, t + 5)
        COMPP(s2h0, s2h1, s2l0, s2l1, cc2, t + 2)
        LOADP(s2h0, s2h1, s2l0, s2l1, cc2, t + 6)
        COMPP(s3h0, s3h1, s3l0, s3l1, cc3, t + 3)
    }
#undef COMPP
#undef LOADP

    // cross-lane top-2 merge over the 16 centroid columns (within K-half)
#pragma unroll
    for (int off = 1; off < 16; off <<= 1) {
#pragma unroll
        for (int e = 0; e < 16; ++e) {
            float o1 = __shfl_xor(b1[e], off, 64);
            float o2 = __shfl_xor(b2[e], off, 64);
            int   ok = __shfl_xor(bk[e], off, 64);
            bool take = (o1 < b1[e]) || (o1 == b1[e] && ok < bk[e]);
            float nb2 = take ? fminf(b1[e], o2) : fminf(b2[e], o1);
            b1[e] = take ? o1 : b1[e];
            bk[e] = take ? ok : bk[e];
            b2[e] = nb2;
        }
    }

    // per-half results -> LDS
    if (col == 0) {
#pragma unroll
        for (int e = 0; e < 16; ++e) {
            const int mi = e >> 2, r = e & 3;
            const int p = rg * 64 + mi * 16 + quad * 4 + r;   // 0..127
            smb1[kh][p] = b1[e];
            smb2[kh][p] = b2[e];
            smbk[kh][p] = bk[e];
        }
    }
    __syncthreads();

    // merge the two K-halves per point (lexicographic (s,k); half 0 holds
    // the lower k-range, so ties resolve to it naturally).
    if (tid < 128) {
        const int p = tid;
        float b1a = smb1[0][p], b2a = smb2[0][p];
        int   bka = smbk[0][p];
        float b1b = smb1[1][p], b2b = smb2[1][p];
        int   bkb = smbk[1][p];
        bool take = (b1b < b1a) || (b1b == b1a && bkb < bka);
        float m1 = take ? b1b : b1a;
        int   mk = take ? bkb : bka;
        float m2 = take ? fminf(b1a, b2b) : fminf(b2a, b1b);
        sbk[p] = mk;
        out_bin[mb + p] = (float)mk;
        if (m2 - m1 < EPS) {
            int idx = atomicAdd(counter, 1);
            flags[idx] = mb + p;
        }
    }
    __syncthreads();

    // exact fp32 residuals for the block's 128 points (2048 float4s).
#pragma unroll
    for (int j = 0; j < 8; ++j) {
        const int idx = j * 256 + tid;
        const int row = idx >> 4, c4 = idx & 15;
        const int bki = sbk[row];
        float4 av = ((const float4*)(action + (size_t)(mb + row) * D))[c4];
        float4 cv = ((const float4*)centroids)[bki * 16 + c4];
        ((float4*)(out_res + (size_t)(mb + row) * D))[c4] =
            make_float4(av.x - cv.x, av.y - cv.y, av.z - cv.z, av.w - cv.w);
    }
}

// Exact fp32 rescan for flagged points. Block-per-point grid-stride.
// (round-0 known-good version)
__global__ __launch_bounds__(256) void exact_kernel(
    const float* __restrict__ action, const float* __restrict__ centroids,
    const float* __restrict__ c2, const int* __restrict__ counter,
    const int* __restrict__ flags, float* __restrict__ out_bin,
    float* __restrict__ out_res, int K) {
    __shared__ float4 sa[D / 4];
    __shared__ float  swv[4];
    __shared__ int    swk[4];
    __shared__ int    s_bk;
    const int count = *counter;
    const int tid = threadIdx.x, lane = tid & 63, wid = tid >> 6;
    for (int i = blockIdx.x; i < count; i += gridDim.x) {
        const int n = flags[i];
        __syncthreads();
        if (tid < D / 4) sa[tid] = ((const float4*)(action + (size_t)n * D))[tid];
        __syncthreads();
        float best = __builtin_inff();
        int bbk = 0x7fffffff;
        for (int k = tid; k < K; k += 256) {
            const float4* cr = (const float4*)(centroids + (size_t)k * D);
            float d0 = 0.f, d1 = 0.f, d2 = 0.f, d3 = 0.f;
#pragma unroll
            for (int q = 0; q < 4; ++q) {
                float4 a0 = sa[q * 4 + 0], c0 = cr[q * 4 + 0];
                float4 a1 = sa[q * 4 + 1], c1 = cr[q * 4 + 1];
                float4 a2 = sa[q * 4 + 2], c2v = cr[q * 4 + 2];
                float4 a3 = sa[q * 4 + 3], c3 = cr[q * 4 + 3];
                d0 = fmaf(a0.x, c0.x, d0); d0 = fmaf(a0.y, c0.y, d0);
                d0 = fmaf(a0.z, c0.z, d0); d0 = fmaf(a0.w, c0.w, d0);
                d1 = fmaf(a1.x, c1.x, d1); d1 = fmaf(a1.y, c1.y, d1);
                d1 = fmaf(a1.z, c1.z, d1); d1 = fmaf(a1.w, c1.w, d1);
                d2 = fmaf(a2.x, c2v.x, d2); d2 = fmaf(a2.y, c2v.y, d2);
                d2 = fmaf(a2.z, c2v.z, d2); d2 = fmaf(a2.w, c2v.w, d2);
                d3 = fmaf(a3.x, c3.x, d3); d3 = fmaf(a3.y, c3.y, d3);
                d3 = fmaf(a3.z, c3.z, d3); d3 = fmaf(a3.w, c3.w, d3);
            }
            float dot = (d0 + d1) + (d2 + d3);
            float s = fmaf(-2.f, dot, c2[k]);
            if (s < best) { best = s; bbk = k; }  // ascending k: first-min
        }
#pragma unroll
        for (int off = 32; off > 0; off >>= 1) {
            float ov = __shfl_down(best, off, 64);
            int   ok = __shfl_down(bbk, off, 64);
            if (ov < best || (ov == best && ok < bbk)) { best = ov; bbk = ok; }
        }
        if (lane == 0) { swv[wid] = best; swk[wid] = bbk; }
        __syncthreads();
        if (tid == 0) {
            float bb = swv[0]; int bki = swk[0];
#pragma unroll
            for (int t = 1; t < 4; ++t)
                if (swv[t] < bb || (swv[t] == bb && swk[t] < bki)) {
                    bb = swv[t]; bki = swk[t];
                }
            out_bin[n] = (float)bki;
            s_bk = bki;
        }
        __syncthreads();
        if (tid < D / 4) {
            float4 a = sa[tid];
            float4 c = ((const float4*)(centroids + (size_t)s_bk * D))[tid];
            ((float4*)(out_res + (size_t)n * D))[tid] =
                make_float4(a.x - c.x, a.y - c.y, a.z - c.z, a.w - c.w);
        }
    }
}

extern "C" void kernel_launch(void* const* d_in, const int* in_sizes, int n_in,
                              void* d_out, int out_size, void* d_ws, size_t ws_size,
                              hipStream_t stream) {
    const float* action    = (const float*)d_in[0];  // [N, 64]
    const float* centroids = (const float*)d_in[1];  // [K, 64]
    const int N = in_sizes[0] / D;  // 65536
    const int K = in_sizes[1] / D;  // 2048

    float* out_bin = (float*)d_out;      // N floats: argmin index
    float* out_res = (float*)d_out + N;  // N*D residuals

    // ws layout (~0.8 MB)
    char* w = (char*)d_ws;
    float*     c2      = (float*)w;                       // 8 KB
    int*       counter = (int*)(w + 8192);                // 4 B (padded to 256)
    int*       flags   = (int*)(w + 8448);                // N*4 = 256 KB
    _Float16*  chs     = (_Float16*)(w + 8448 + 262144);  // K*D*2 = 256 KB (swizzled)
    _Float16*  cls     = chs + (size_t)K * D;             // 256 KB (swizzled)

    prep_kernel<<<(K * 8 + 255) / 256, 256, 0, stream>>>(centroids, chs, cls,
                                                         c2, K, counter);
    pass1_kernel<<<N / 128, 256, 0, stream>>>(action, chs, cls, c2, centroids,
                                              out_bin, out_res, counter, flags,
                                              N, K);
    exact_kernel<<<256, 256, 0, stream>>>(action, centroids, c2, counter, flags,
                                          out_bin, out_res, K);
}